// Round 1
// baseline (795.226 us; speedup 1.0000x reference)
//
#include <hip/hip_runtime.h>
#include <stdint.h>

typedef unsigned short u16;
typedef __attribute__((ext_vector_type(4))) float f32x4;
typedef __attribute__((ext_vector_type(8))) short bf16x8;   // 8 bf16 in 4 VGPRs (MFMA A/B frag)
typedef __attribute__((ext_vector_type(8))) unsigned short u16x8;

__device__ __forceinline__ u16 f2b(float f) {
    union { float f; unsigned u; } x; x.f = f;
    unsigned r = x.u + 0x7fffu + ((x.u >> 16) & 1u);   // RNE
    return (u16)(r >> 16);
}
__device__ __forceinline__ float b2f(u16 b) {
    union { unsigned u; float f; } x; x.u = ((unsigned)b) << 16;
    return x.f;
}

// ---------------- cast x (f32) -> bf16 ----------------
__global__ __launch_bounds__(256) void k_cast(const float* __restrict__ s, u16* __restrict__ d) {
    size_t i = (size_t)blockIdx.x * 256 + threadIdx.x;   // handles 8 elems
    const f32x4* sp = (const f32x4*)(s + i * 8);
    f32x4 a = sp[0], b = sp[1];
    u16x8 o;
    o[0] = f2b(a[0]); o[1] = f2b(a[1]); o[2] = f2b(a[2]); o[3] = f2b(a[3]);
    o[4] = f2b(b[0]); o[5] = f2b(b[1]); o[6] = f2b(b[2]); o[7] = f2b(b[3]);
    *(u16x8*)(d + i * 8) = o;
}

// ---------- transpose-cast: dst[(off+m)*stride + k] = src[k*M + m] ----------
__global__ __launch_bounds__(256) void k_transpose(const float* __restrict__ src, u16* __restrict__ dst,
                                                   int M, int dstOff, int dstStride) {
    __shared__ float t[32][33];
    int bx = blockIdx.x * 32;   // k
    int by = blockIdx.y * 32;   // m
    int tx = threadIdx.x & 31, ty = threadIdx.x >> 5;
#pragma unroll
    for (int r = 0; r < 32; r += 8)
        t[ty + r][tx] = src[(size_t)(bx + ty + r) * M + by + tx];
    __syncthreads();
#pragma unroll
    for (int r = 0; r < 32; r += 8)
        dst[(size_t)(dstOff + by + ty + r) * dstStride + bx + tx] = f2b(t[tx][ty + r]);
}

// ---------------- GEMM: C[N,M](bf16) = A[N,K](bf16) @ BT[M,K](bf16)^T + epilogue ----------------
// EPI 0: QKV (bias cat + rel_h/rel_w). EPI 1: bias + exact GELU. EPI 2: bias.
template<int EPI>
__global__ __launch_bounds__(256) void k_gemm(
    const u16* __restrict__ A, const u16* __restrict__ BT, u16* __restrict__ C, int K,
    const float* __restrict__ bias0, const float* __restrict__ bias1, const float* __restrict__ bias2,
    const float* __restrict__ relh, const float* __restrict__ relw)
{
    __shared__ __align__(16) u16 As[128 * 64];
    __shared__ __align__(16) u16 Bs[128 * 64];
    const int lane = threadIdx.x & 63;
    const int wid  = threadIdx.x >> 6;
    const int rowBase = blockIdx.x * 128;
    const int colBase = blockIdx.y * 128;
    const int M  = (int)gridDim.y * 128;   // == ldc for all our launches
    const int wr = (wid >> 1) * 64;
    const int wc = (wid & 1) * 64;

    // staging: inst i covers rows i*8..i*8+8 of the tile; lane l -> row i*8+(l>>3),
    // LDS chunk (l&7). XOR-swizzle (T2): LDS slot chunk s of row r holds logical
    // chunk s^(r&7) -> pre-swizzle the GLOBAL source column (gload_lds writes linearly).
    const int srow   = lane >> 3;
    const int schunk = (lane & 7) ^ srow;

    f32x4 acc[4][4] = {};

    const u16* gA = A  + (size_t)(rowBase + srow) * K + schunk * 8;
    const u16* gB = BT + (size_t)(colBase + srow) * K + schunk * 8;

    for (int k0 = 0; k0 < K; k0 += 64) {
#pragma unroll
        for (int i = 0; i < 4; ++i) {
            int ii = i * 4 + wid;
            __builtin_amdgcn_global_load_lds(
                (const __attribute__((address_space(1))) void*)(gA + (size_t)ii * 8 * K + k0),
                (__attribute__((address_space(3))) void*)&As[ii * 512], 16, 0, 0);
            __builtin_amdgcn_global_load_lds(
                (const __attribute__((address_space(1))) void*)(gB + (size_t)ii * 8 * K + k0),
                (__attribute__((address_space(3))) void*)&Bs[ii * 512], 16, 0, 0);
        }
        __syncthreads();
#pragma unroll
        for (int kk = 0; kk < 2; ++kk) {
            const int cc = (kk * 4 + (lane >> 4)) ^ (lane & 7);   // row&7 == lane&7 here
            bf16x8 af[4], bfr[4];
#pragma unroll
            for (int m = 0; m < 4; ++m) {
                int row = wr + m * 16 + (lane & 15);
                af[m] = *(const bf16x8*)&As[row * 64 + cc * 8];
            }
#pragma unroll
            for (int n = 0; n < 4; ++n) {
                int row = wc + n * 16 + (lane & 15);
                bfr[n] = *(const bf16x8*)&Bs[row * 64 + cc * 8];
            }
#pragma unroll
            for (int m = 0; m < 4; ++m)
#pragma unroll
                for (int n = 0; n < 4; ++n)
                    acc[m][n] = __builtin_amdgcn_mfma_f32_16x16x32_bf16(af[m], bfr[n], acc[m][n], 0, 0, 0);
        }
        __syncthreads();
    }

    // epilogue; C/D layout: col = lane&15, row = (lane>>4)*4 + reg  [m89/m91 verified]
#pragma unroll
    for (int m = 0; m < 4; ++m) {
        int grow0 = rowBase + wr + m * 16 + ((lane >> 4) << 2);
#pragma unroll
        for (int n = 0; n < 4; ++n) {
            int gcol = colBase + wc + n * 16 + (lane & 15);
            float badd;
            if (EPI == 0) {
                badd = (gcol < 64) ? bias0[gcol] : (gcol < 128 ? bias1[gcol - 64] : bias2[gcol - 128]);
            } else {
                badd = bias0[gcol];
            }
#pragma unroll
            for (int p = 0; p < 4; ++p) {
                int r = grow0 + p;
                float v = acc[m][n][p] + badd;
                if (EPI == 0) {
                    if (gcol < 64)        v += relh[(((r >> 6) & 63) << 6) + gcol];
                    else if (gcol < 128)  v += relw[((r & 63) << 6) + (gcol - 64)];
                } else if (EPI == 1) {
                    v = 0.5f * v * (1.0f + erff(v * 0.70710678118654752f));
                }
                C[(size_t)r * M + gcol] = f2b(v);
            }
        }
    }
}

// ---------------- axial attention: one block per (b,h); W=64, d=64, E=512 ----------------
__global__ __launch_bounds__(256) void k_attn(const u16* __restrict__ qkv, u16* __restrict__ ao) {
    __shared__ __align__(16) u16 vsT[512 * 64];   // v transposed [col E][row W], XOR-swizzled
    __shared__ __align__(16) u16 ps[64 * 72];     // P bf16, padded stride 72
    const int lane = threadIdx.x & 63;
    const int wid  = threadIdx.x >> 6;
    const int t    = threadIdx.x;
    const size_t base = (size_t)blockIdx.x * 64;

    // stage v (cols 128..640 of qkv rows) transposed into LDS, swizzled chunks
    for (int it = 0; it < 16; ++it) {
        int idx = t + it * 256;
        int j   = idx >> 6;            // v row (width pos)
        int c0  = (idx & 63) * 8;      // v col chunk
        bf16x8 vv = *(const bf16x8*)(qkv + (base + j) * 640 + 128 + c0);
#pragma unroll
        for (int e = 0; e < 8; ++e) {
            int c = c0 + e;
            vsT[c * 64 + (j ^ ((c & 7) << 3))] = (u16)vv[e];
        }
    }

    // S = q k^T for this wave's 16 query rows (frags straight from global, NT pattern)
    const int r0 = wid * 16;
    const int g  = lane >> 4;
    bf16x8 qa[2];
#pragma unroll
    for (int kk = 0; kk < 2; ++kk)
        qa[kk] = *(const bf16x8*)(qkv + (base + r0 + (lane & 15)) * 640 + kk * 32 + (g << 3));
    f32x4 s[4] = {};
#pragma unroll
    for (int n = 0; n < 4; ++n)
#pragma unroll
        for (int kk = 0; kk < 2; ++kk) {
            bf16x8 kb = *(const bf16x8*)(qkv + (base + n * 16 + (lane & 15)) * 640 + 64 + kk * 32 + (g << 3));
            s[n] = __builtin_amdgcn_mfma_f32_16x16x32_bf16(qa[kk], kb, s[n], 0, 0, 0);
        }

    // wave-parallel softmax over 64 cols; row r=(r0+g*4+p) lives in 16 lanes (same g)
    float mx[4], sm[4], inv[4];
    float pe[4][4];
#pragma unroll
    for (int p = 0; p < 4; ++p)
        mx[p] = fmaxf(fmaxf(s[0][p], s[1][p]), fmaxf(s[2][p], s[3][p]));
#pragma unroll
    for (int d = 1; d < 16; d <<= 1)
#pragma unroll
        for (int p = 0; p < 4; ++p) mx[p] = fmaxf(mx[p], __shfl_xor(mx[p], d));
#pragma unroll
    for (int p = 0; p < 4; ++p) sm[p] = 0.f;
#pragma unroll
    for (int n = 0; n < 4; ++n)
#pragma unroll
        for (int p = 0; p < 4; ++p) { pe[n][p] = __expf(s[n][p] - mx[p]); sm[p] += pe[n][p]; }
#pragma unroll
    for (int d = 1; d < 16; d <<= 1)
#pragma unroll
        for (int p = 0; p < 4; ++p) sm[p] += __shfl_xor(sm[p], d);
#pragma unroll
    for (int p = 0; p < 4; ++p) inv[p] = 1.f / sm[p];
#pragma unroll
    for (int n = 0; n < 4; ++n)
#pragma unroll
        for (int p = 0; p < 4; ++p)
            ps[(r0 + (g << 2) + p) * 72 + n * 16 + (lane & 15)] = f2b(pe[n][p] * inv[p]);

    __syncthreads();   // vsT staged by all threads; ps is same-wave

    // O = P @ v : A-frag from own ps rows, B-frag = ds_read_b128 from swizzled vsT
    bf16x8 pa[2];
#pragma unroll
    for (int kk = 0; kk < 2; ++kk)
        pa[kk] = *(const bf16x8*)&ps[(r0 + (lane & 15)) * 72 + kk * 32 + (g << 3)];
    for (int n = 0; n < 32; ++n) {
        f32x4 o = {};
#pragma unroll
        for (int kk = 0; kk < 2; ++kk) {
            int c  = n * 16 + (lane & 15);
            int cl = kk * 4 + g;
            bf16x8 vb = *(const bf16x8*)&vsT[c * 64 + ((cl ^ (c & 7)) << 3)];
            o = __builtin_amdgcn_mfma_f32_16x16x32_bf16(pa[kk], vb, o, 0, 0, 0);
        }
        int col = n * 16 + (lane & 15);
#pragma unroll
        for (int p = 0; p < 4; ++p)
            ao[(base + r0 + (g << 2) + p) * 512 + col] = f2b(o[p]);
    }
}

// ---------------- LN1: h1 = LN(x + ao) -> bf16 ----------------
__global__ __launch_bounds__(256) void k_ln1(const float* __restrict__ x, const u16* __restrict__ ao,
                                             const float* __restrict__ gw, const float* __restrict__ gb,
                                             u16* __restrict__ h1) {
    const int lane = threadIdx.x & 63;
    const size_t row = (size_t)blockIdx.x * 4 + (threadIdx.x >> 6);
    const size_t off = row * 512 + lane * 8;
    f32x4 x0 = *(const f32x4*)(x + off), x1 = *(const f32x4*)(x + off + 4);
    u16x8 a = *(const u16x8*)(ao + off);
    float v[8];
    v[0]=x0[0]+b2f(a[0]); v[1]=x0[1]+b2f(a[1]); v[2]=x0[2]+b2f(a[2]); v[3]=x0[3]+b2f(a[3]);
    v[4]=x1[0]+b2f(a[4]); v[5]=x1[1]+b2f(a[5]); v[6]=x1[2]+b2f(a[6]); v[7]=x1[3]+b2f(a[7]);
    float s = 0.f, q = 0.f;
#pragma unroll
    for (int i = 0; i < 8; ++i) { s += v[i]; q += v[i] * v[i]; }
#pragma unroll
    for (int d = 1; d < 64; d <<= 1) { s += __shfl_xor(s, d); q += __shfl_xor(q, d); }
    float mean = s * (1.f / 512.f);
    float var  = q * (1.f / 512.f) - mean * mean;
    float rstd = rsqrtf(var + 1e-5f);
    u16x8 o;
#pragma unroll
    for (int i = 0; i < 8; ++i)
        o[i] = f2b((v[i] - mean) * rstd * gw[lane * 8 + i] + gb[lane * 8 + i]);
    *(u16x8*)(h1 + off) = o;
}

// ---------------- LN2: out = LN(h1 + ffn) -> f32 ----------------
__global__ __launch_bounds__(256) void k_ln2(const u16* __restrict__ h1, const u16* __restrict__ ff,
                                             const float* __restrict__ gw, const float* __restrict__ gb,
                                             float* __restrict__ out) {
    const int lane = threadIdx.x & 63;
    const size_t row = (size_t)blockIdx.x * 4 + (threadIdx.x >> 6);
    const size_t off = row * 512 + lane * 8;
    u16x8 a = *(const u16x8*)(h1 + off);
    u16x8 c = *(const u16x8*)(ff + off);
    float v[8];
#pragma unroll
    for (int i = 0; i < 8; ++i) v[i] = b2f(a[i]) + b2f(c[i]);
    float s = 0.f, q = 0.f;
#pragma unroll
    for (int i = 0; i < 8; ++i) { s += v[i]; q += v[i] * v[i]; }
#pragma unroll
    for (int d = 1; d < 64; d <<= 1) { s += __shfl_xor(s, d); q += __shfl_xor(q, d); }
    float mean = s * (1.f / 512.f);
    float var  = q * (1.f / 512.f) - mean * mean;
    float rstd = rsqrtf(var + 1e-5f);
    f32x4 o0, o1;
#pragma unroll
    for (int i = 0; i < 4; ++i) o0[i] = (v[i] - mean) * rstd * gw[lane * 8 + i] + gb[lane * 8 + i];
#pragma unroll
    for (int i = 0; i < 4; ++i) o1[i] = (v[4 + i] - mean) * rstd * gw[lane * 8 + 4 + i] + gb[lane * 8 + 4 + i];
    *(f32x4*)(out + off) = o0;
    *(f32x4*)(out + off + 4) = o1;
}

extern "C" void kernel_launch(void* const* d_in, const int* in_sizes, int n_in,
                              void* d_out, int out_size, void* d_ws, size_t ws_size,
                              hipStream_t stream) {
    const float* x    = (const float*)d_in[0];
    const float* Wq   = (const float*)d_in[1];
    const float* bq   = (const float*)d_in[2];
    const float* Wk   = (const float*)d_in[3];
    const float* bk   = (const float*)d_in[4];
    const float* Wv   = (const float*)d_in[5];
    const float* bv   = (const float*)d_in[6];
    const float* relh = (const float*)d_in[7];
    const float* relw = (const float*)d_in[8];
    const float* g1   = (const float*)d_in[9];
    const float* bb1  = (const float*)d_in[10];
    const float* W1   = (const float*)d_in[11];
    const float* b1   = (const float*)d_in[12];
    const float* W2   = (const float*)d_in[13];
    const float* b2   = (const float*)d_in[14];
    const float* g2   = (const float*)d_in[15];
    const float* bb2  = (const float*)d_in[16];
    float* out = (float*)d_out;

    // workspace layout (407,502,848 bytes total); u aliases dead xb/qkv/ao regions
    char* ws = (char*)d_ws;
    u16* u     = (u16*)(ws + 0);                        // [N][2048] bf16, FFN mid
    u16* xb    = (u16*)(ws + 0);                        // [N][512]  (dead before u written)
    u16* qkv   = (u16*)(ws + 67108864ull);              // [N][640]  (dead before u written)
    u16* ao    = (u16*)(ws + 150994944ull);             // [N][512]  (dead before u written)
    u16* h1    = (u16*)(ws + 268435456ull);             // [N][512]
    u16* ff2   = (u16*)(ws + 335544320ull);             // [N][512]
    u16* wqkvT = (u16*)(ws + 402653184ull);             // [640][512]
    u16* w1T   = (u16*)(ws + 403308544ull);             // [2048][512]
    u16* w2T   = (u16*)(ws + 405405696ull);             // [512][2048]

    // weight transposes (bf16, B^T layout for NT GEMM)
    k_transpose<<<dim3(16, 2),  256, 0, stream>>>(Wq, wqkvT, 64,   0,   512);
    k_transpose<<<dim3(16, 2),  256, 0, stream>>>(Wk, wqkvT, 64,   64,  512);
    k_transpose<<<dim3(16, 16), 256, 0, stream>>>(Wv, wqkvT, 512,  128, 512);
    k_transpose<<<dim3(16, 64), 256, 0, stream>>>(W1, w1T,   2048, 0,   512);
    k_transpose<<<dim3(64, 16), 256, 0, stream>>>(W2, w2T,   512,  0,   2048);

    k_cast<<<16384, 256, 0, stream>>>(x, xb);

    // fused QKV projection (+bias, +rel_h on q, +rel_w on k): [N][640]
    k_gemm<0><<<dim3(512, 5),  256, 0, stream>>>(xb, wqkvT, qkv, 512, bq, bk, bv, relh, relw);
    k_attn<<<1024, 256, 0, stream>>>(qkv, ao);
    k_ln1<<<16384, 256, 0, stream>>>(x, ao, g1, bb1, h1);
    k_gemm<1><<<dim3(512, 16), 256, 0, stream>>>(h1, w1T, u,   512,  b1, nullptr, nullptr, nullptr, nullptr);
    k_gemm<2><<<dim3(512, 4),  256, 0, stream>>>(u,  w2T, ff2, 2048, b2, nullptr, nullptr, nullptr, nullptr);
    k_ln2<<<16384, 256, 0, stream>>>(h1, ff2, g2, bb2, out);
}

// Round 2
// 722.721 us; speedup vs baseline: 1.1003x; 1.1003x over previous
//
#include <hip/hip_runtime.h>
#include <stdint.h>

typedef unsigned short u16;
typedef __attribute__((ext_vector_type(4))) float f32x4;
typedef __attribute__((ext_vector_type(8))) short bf16x8;   // 8 bf16 in 4 VGPRs (MFMA A/B frag)
typedef __attribute__((ext_vector_type(8))) unsigned short u16x8;

__device__ __forceinline__ u16 f2b(float f) {
    union { float f; unsigned u; } x; x.f = f;
    unsigned r = x.u + 0x7fffu + ((x.u >> 16) & 1u);   // RNE
    return (u16)(r >> 16);
}
__device__ __forceinline__ float b2f(u16 b) {
    union { unsigned u; float f; } x; x.u = ((unsigned)b) << 16;
    return x.f;
}

// ---------------- cast x (f32) -> bf16 ----------------
__global__ __launch_bounds__(256) void k_cast(const float* __restrict__ s, u16* __restrict__ d) {
    size_t i = (size_t)blockIdx.x * 256 + threadIdx.x;   // handles 8 elems
    const f32x4* sp = (const f32x4*)(s + i * 8);
    f32x4 a = sp[0], b = sp[1];
    u16x8 o;
    o[0] = f2b(a[0]); o[1] = f2b(a[1]); o[2] = f2b(a[2]); o[3] = f2b(a[3]);
    o[4] = f2b(b[0]); o[5] = f2b(b[1]); o[6] = f2b(b[2]); o[7] = f2b(b[3]);
    *(u16x8*)(d + i * 8) = o;
}

// ---------- transpose-cast: dst[(off+m)*stride + k] = src[k*M + m] ----------
__global__ __launch_bounds__(256) void k_transpose(const float* __restrict__ src, u16* __restrict__ dst,
                                                   int M, int dstOff, int dstStride) {
    __shared__ float t[32][33];
    int bx = blockIdx.x * 32;   // k
    int by = blockIdx.y * 32;   // m
    int tx = threadIdx.x & 31, ty = threadIdx.x >> 5;
#pragma unroll
    for (int r = 0; r < 32; r += 8)
        t[ty + r][tx] = src[(size_t)(bx + ty + r) * M + by + tx];
    __syncthreads();
#pragma unroll
    for (int r = 0; r < 32; r += 8)
        dst[(size_t)(dstOff + by + ty + r) * dstStride + bx + tx] = f2b(t[tx][ty + r]);
}

// ---- block -> (rowTile, colTile): XCD bijective chunk swizzle (m204) + supertile ----
// Supertile = G row-tiles x all nC col-tiles; consecutive logical ids walk rows
// within a supertile first, so the B col-panel is reused G times back-to-back and
// the G A-panels stay resident in the XCD-local L2 across the nC column sweep.
__device__ __forceinline__ void tile_map(int bid, int nR, int nC, int G, int& tr, int& tc) {
    int nwg = nR * nC;
    int q = nwg >> 3, r8 = nwg & 7;
    int xcd = bid & 7, idx = bid >> 3;
    int swz = (xcd < r8 ? xcd * (q + 1) : r8 * (q + 1) + (xcd - r8) * q) + idx;
    int per = G * nC;
    int s = swz / per, w = swz % per;
    int rbase = s * G;
    int g = nR - rbase; if (g > G) g = G;   // tail supertile
    tr = rbase + w % g;
    tc = w / g;
}

// ---------------- GEMM: C[N,M](bf16) = A[N,K](bf16) @ BT[M,K](bf16)^T + epilogue ----------------
// EPI 0: QKV (bias cat + rel_h/rel_w). EPI 1: bias + exact GELU. EPI 2: bias.
template<int EPI>
__global__ __launch_bounds__(256) void k_gemm(
    const u16* __restrict__ A, const u16* __restrict__ BT, u16* __restrict__ C, int K,
    int M, int nR, int nC, int G,
    const float* __restrict__ bias0, const float* __restrict__ bias1, const float* __restrict__ bias2,
    const float* __restrict__ relh, const float* __restrict__ relw)
{
    __shared__ __align__(16) u16 As[128 * 64];
    __shared__ __align__(16) u16 Bs[128 * 64];
    const int lane = threadIdx.x & 63;
    const int wid  = threadIdx.x >> 6;
    int tr, tc;
    tile_map((int)blockIdx.x, nR, nC, G, tr, tc);
    const int rowBase = tr * 128;
    const int colBase = tc * 128;
    const int wr = (wid >> 1) * 64;
    const int wc = (wid & 1) * 64;

    // staging: inst i covers rows i*8..i*8+8 of the tile; lane l -> row i*8+(l>>3),
    // LDS chunk (l&7). XOR-swizzle (T2): LDS slot chunk s of row r holds logical
    // chunk s^(r&7) -> pre-swizzle the GLOBAL source column (gload_lds writes linearly).
    const int srow   = lane >> 3;
    const int schunk = (lane & 7) ^ srow;

    f32x4 acc[4][4] = {};

    const u16* gA = A  + (size_t)(rowBase + srow) * K + schunk * 8;
    const u16* gB = BT + (size_t)(colBase + srow) * K + schunk * 8;

    for (int k0 = 0; k0 < K; k0 += 64) {
#pragma unroll
        for (int i = 0; i < 4; ++i) {
            int ii = i * 4 + wid;
            __builtin_amdgcn_global_load_lds(
                (const __attribute__((address_space(1))) void*)(gA + (size_t)ii * 8 * K + k0),
                (__attribute__((address_space(3))) void*)&As[ii * 512], 16, 0, 0);
            __builtin_amdgcn_global_load_lds(
                (const __attribute__((address_space(1))) void*)(gB + (size_t)ii * 8 * K + k0),
                (__attribute__((address_space(3))) void*)&Bs[ii * 512], 16, 0, 0);
        }
        __syncthreads();
#pragma unroll
        for (int kk = 0; kk < 2; ++kk) {
            const int cc = (kk * 4 + (lane >> 4)) ^ (lane & 7);   // row&7 == lane&7 here
            bf16x8 af[4], bfr[4];
#pragma unroll
            for (int m = 0; m < 4; ++m) {
                int row = wr + m * 16 + (lane & 15);
                af[m] = *(const bf16x8*)&As[row * 64 + cc * 8];
            }
#pragma unroll
            for (int n = 0; n < 4; ++n) {
                int row = wc + n * 16 + (lane & 15);
                bfr[n] = *(const bf16x8*)&Bs[row * 64 + cc * 8];
            }
#pragma unroll
            for (int m = 0; m < 4; ++m)
#pragma unroll
                for (int n = 0; n < 4; ++n)
                    acc[m][n] = __builtin_amdgcn_mfma_f32_16x16x32_bf16(af[m], bfr[n], acc[m][n], 0, 0, 0);
        }
        __syncthreads();
    }

    // epilogue; C/D layout: col = lane&15, row = (lane>>4)*4 + reg  [m89/m91 verified]
#pragma unroll
    for (int m = 0; m < 4; ++m) {
        int grow0 = rowBase + wr + m * 16 + ((lane >> 4) << 2);
#pragma unroll
        for (int n = 0; n < 4; ++n) {
            int gcol = colBase + wc + n * 16 + (lane & 15);
            float badd;
            if (EPI == 0) {
                badd = (gcol < 64) ? bias0[gcol] : (gcol < 128 ? bias1[gcol - 64] : bias2[gcol - 128]);
            } else {
                badd = bias0[gcol];
            }
#pragma unroll
            for (int p = 0; p < 4; ++p) {
                int r = grow0 + p;
                float v = acc[m][n][p] + badd;
                if (EPI == 0) {
                    if (gcol < 64)        v += relh[(((r >> 6) & 63) << 6) + gcol];
                    else if (gcol < 128)  v += relw[((r & 63) << 6) + (gcol - 64)];
                } else if (EPI == 1) {
                    v = 0.5f * v * (1.0f + erff(v * 0.70710678118654752f));
                }
                C[(size_t)r * M + gcol] = f2b(v);
            }
        }
    }
}

// ---------------- axial attention: one block per (b,h); W=64, d=64, E=512 ----------------
__global__ __launch_bounds__(256) void k_attn(const u16* __restrict__ qkv, u16* __restrict__ ao) {
    __shared__ __align__(16) u16 vsT[512 * 64];   // v transposed [col E][row W], XOR-swizzled
    __shared__ __align__(16) u16 ps[64 * 72];     // P bf16, padded stride 72
    const int lane = threadIdx.x & 63;
    const int wid  = threadIdx.x >> 6;
    const int t    = threadIdx.x;
    const size_t base = (size_t)blockIdx.x * 64;

    // stage v (cols 128..640 of qkv rows) transposed into LDS, swizzled chunks
    for (int it = 0; it < 16; ++it) {
        int idx = t + it * 256;
        int j   = idx >> 6;            // v row (width pos)
        int c0  = (idx & 63) * 8;      // v col chunk
        bf16x8 vv = *(const bf16x8*)(qkv + (base + j) * 640 + 128 + c0);
#pragma unroll
        for (int e = 0; e < 8; ++e) {
            int c = c0 + e;
            vsT[c * 64 + (j ^ ((c & 7) << 3))] = (u16)vv[e];
        }
    }

    // S = q k^T for this wave's 16 query rows (frags straight from global, NT pattern)
    const int r0 = wid * 16;
    const int g  = lane >> 4;
    bf16x8 qa[2];
#pragma unroll
    for (int kk = 0; kk < 2; ++kk)
        qa[kk] = *(const bf16x8*)(qkv + (base + r0 + (lane & 15)) * 640 + kk * 32 + (g << 3));
    f32x4 s[4] = {};
#pragma unroll
    for (int n = 0; n < 4; ++n)
#pragma unroll
        for (int kk = 0; kk < 2; ++kk) {
            bf16x8 kb = *(const bf16x8*)(qkv + (base + n * 16 + (lane & 15)) * 640 + 64 + kk * 32 + (g << 3));
            s[n] = __builtin_amdgcn_mfma_f32_16x16x32_bf16(qa[kk], kb, s[n], 0, 0, 0);
        }

    // wave-parallel softmax over 64 cols; row r=(r0+g*4+p) lives in 16 lanes (same g)
    float mx[4], sm[4], inv[4];
    float pe[4][4];
#pragma unroll
    for (int p = 0; p < 4; ++p)
        mx[p] = fmaxf(fmaxf(s[0][p], s[1][p]), fmaxf(s[2][p], s[3][p]));
#pragma unroll
    for (int d = 1; d < 16; d <<= 1)
#pragma unroll
        for (int p = 0; p < 4; ++p) mx[p] = fmaxf(mx[p], __shfl_xor(mx[p], d));
#pragma unroll
    for (int p = 0; p < 4; ++p) sm[p] = 0.f;
#pragma unroll
    for (int n = 0; n < 4; ++n)
#pragma unroll
        for (int p = 0; p < 4; ++p) { pe[n][p] = __expf(s[n][p] - mx[p]); sm[p] += pe[n][p]; }
#pragma unroll
    for (int d = 1; d < 16; d <<= 1)
#pragma unroll
        for (int p = 0; p < 4; ++p) sm[p] += __shfl_xor(sm[p], d);
#pragma unroll
    for (int p = 0; p < 4; ++p) inv[p] = 1.f / sm[p];
#pragma unroll
    for (int n = 0; n < 4; ++n)
#pragma unroll
        for (int p = 0; p < 4; ++p)
            ps[(r0 + (g << 2) + p) * 72 + n * 16 + (lane & 15)] = f2b(pe[n][p] * inv[p]);

    __syncthreads();   // vsT staged by all threads; ps is same-wave

    // O = P @ v : A-frag from own ps rows, B-frag = ds_read_b128 from swizzled vsT
    bf16x8 pa[2];
#pragma unroll
    for (int kk = 0; kk < 2; ++kk)
        pa[kk] = *(const bf16x8*)&ps[(r0 + (lane & 15)) * 72 + kk * 32 + (g << 3)];
    for (int n = 0; n < 32; ++n) {
        f32x4 o = {};
#pragma unroll
        for (int kk = 0; kk < 2; ++kk) {
            int c  = n * 16 + (lane & 15);
            int cl = kk * 4 + g;
            bf16x8 vb = *(const bf16x8*)&vsT[c * 64 + ((cl ^ (c & 7)) << 3)];
            o = __builtin_amdgcn_mfma_f32_16x16x32_bf16(pa[kk], vb, o, 0, 0, 0);
        }
        int col = n * 16 + (lane & 15);
#pragma unroll
        for (int p = 0; p < 4; ++p)
            ao[(base + r0 + (g << 2) + p) * 512 + col] = f2b(o[p]);
    }
}

// ---------------- LN1: h1 = LN(x + ao) -> bf16 ----------------
__global__ __launch_bounds__(256) void k_ln1(const float* __restrict__ x, const u16* __restrict__ ao,
                                             const float* __restrict__ gw, const float* __restrict__ gb,
                                             u16* __restrict__ h1) {
    const int lane = threadIdx.x & 63;
    const size_t row = (size_t)blockIdx.x * 4 + (threadIdx.x >> 6);
    const size_t off = row * 512 + lane * 8;
    f32x4 x0 = *(const f32x4*)(x + off), x1 = *(const f32x4*)(x + off + 4);
    u16x8 a = *(const u16x8*)(ao + off);
    float v[8];
    v[0]=x0[0]+b2f(a[0]); v[1]=x0[1]+b2f(a[1]); v[2]=x0[2]+b2f(a[2]); v[3]=x0[3]+b2f(a[3]);
    v[4]=x1[0]+b2f(a[4]); v[5]=x1[1]+b2f(a[5]); v[6]=x1[2]+b2f(a[6]); v[7]=x1[3]+b2f(a[7]);
    float s = 0.f, q = 0.f;
#pragma unroll
    for (int i = 0; i < 8; ++i) { s += v[i]; q += v[i] * v[i]; }
#pragma unroll
    for (int d = 1; d < 64; d <<= 1) { s += __shfl_xor(s, d); q += __shfl_xor(q, d); }
    float mean = s * (1.f / 512.f);
    float var  = q * (1.f / 512.f) - mean * mean;
    float rstd = rsqrtf(var + 1e-5f);
    u16x8 o;
#pragma unroll
    for (int i = 0; i < 8; ++i)
        o[i] = f2b((v[i] - mean) * rstd * gw[lane * 8 + i] + gb[lane * 8 + i]);
    *(u16x8*)(h1 + off) = o;
}

// ---------------- LN2: out = LN(h1 + ffn) -> f32 ----------------
__global__ __launch_bounds__(256) void k_ln2(const u16* __restrict__ h1, const u16* __restrict__ ff,
                                             const float* __restrict__ gw, const float* __restrict__ gb,
                                             float* __restrict__ out) {
    const int lane = threadIdx.x & 63;
    const size_t row = (size_t)blockIdx.x * 4 + (threadIdx.x >> 6);
    const size_t off = row * 512 + lane * 8;
    u16x8 a = *(const u16x8*)(h1 + off);
    u16x8 c = *(const u16x8*)(ff + off);
    float v[8];
#pragma unroll
    for (int i = 0; i < 8; ++i) v[i] = b2f(a[i]) + b2f(c[i]);
    float s = 0.f, q = 0.f;
#pragma unroll
    for (int i = 0; i < 8; ++i) { s += v[i]; q += v[i] * v[i]; }
#pragma unroll
    for (int d = 1; d < 64; d <<= 1) { s += __shfl_xor(s, d); q += __shfl_xor(q, d); }
    float mean = s * (1.f / 512.f);
    float var  = q * (1.f / 512.f) - mean * mean;
    float rstd = rsqrtf(var + 1e-5f);
    f32x4 o0, o1;
#pragma unroll
    for (int i = 0; i < 4; ++i) o0[i] = (v[i] - mean) * rstd * gw[lane * 8 + i] + gb[lane * 8 + i];
#pragma unroll
    for (int i = 0; i < 4; ++i) o1[i] = (v[4 + i] - mean) * rstd * gw[lane * 8 + 4 + i] + gb[lane * 8 + 4 + i];
    *(f32x4*)(out + off) = o0;
    *(f32x4*)(out + off + 4) = o1;
}

extern "C" void kernel_launch(void* const* d_in, const int* in_sizes, int n_in,
                              void* d_out, int out_size, void* d_ws, size_t ws_size,
                              hipStream_t stream) {
    const float* x    = (const float*)d_in[0];
    const float* Wq   = (const float*)d_in[1];
    const float* bq   = (const float*)d_in[2];
    const float* Wk   = (const float*)d_in[3];
    const float* bk   = (const float*)d_in[4];
    const float* Wv   = (const float*)d_in[5];
    const float* bv   = (const float*)d_in[6];
    const float* relh = (const float*)d_in[7];
    const float* relw = (const float*)d_in[8];
    const float* g1   = (const float*)d_in[9];
    const float* bb1  = (const float*)d_in[10];
    const float* W1   = (const float*)d_in[11];
    const float* b1   = (const float*)d_in[12];
    const float* W2   = (const float*)d_in[13];
    const float* b2   = (const float*)d_in[14];
    const float* g2   = (const float*)d_in[15];
    const float* bb2  = (const float*)d_in[16];
    float* out = (float*)d_out;

    // workspace layout (407,502,848 bytes total); u aliases dead xb/qkv/ao regions
    char* ws = (char*)d_ws;
    u16* u     = (u16*)(ws + 0);                        // [N][2048] bf16, FFN mid
    u16* xb    = (u16*)(ws + 0);                        // [N][512]  (dead before u written)
    u16* qkv   = (u16*)(ws + 67108864ull);              // [N][640]  (dead before u written)
    u16* ao    = (u16*)(ws + 150994944ull);             // [N][512]  (dead before u written)
    u16* h1    = (u16*)(ws + 268435456ull);             // [N][512]
    u16* ff2   = (u16*)(ws + 335544320ull);             // [N][512]
    u16* wqkvT = (u16*)(ws + 402653184ull);             // [640][512]
    u16* w1T   = (u16*)(ws + 403308544ull);             // [2048][512]
    u16* w2T   = (u16*)(ws + 405405696ull);             // [512][2048]

    // weight transposes (bf16, B^T layout for NT GEMM)
    k_transpose<<<dim3(16, 2),  256, 0, stream>>>(Wq, wqkvT, 64,   0,   512);
    k_transpose<<<dim3(16, 2),  256, 0, stream>>>(Wk, wqkvT, 64,   64,  512);
    k_transpose<<<dim3(16, 16), 256, 0, stream>>>(Wv, wqkvT, 512,  128, 512);
    k_transpose<<<dim3(16, 64), 256, 0, stream>>>(W1, w1T,   2048, 0,   512);
    k_transpose<<<dim3(64, 16), 256, 0, stream>>>(W2, w2T,   512,  0,   2048);

    k_cast<<<16384, 256, 0, stream>>>(x, xb);

    // fused QKV projection (+bias, +rel_h on q, +rel_w on k): [N][640]
    // G chosen so supertile working set (G*128*K*2 + nC*128*K*2 bytes) fits one XCD's 4MB L2
    k_gemm<0><<<512 * 5,  256, 0, stream>>>(xb, wqkvT, qkv, 512,  640,  512, 5,  8, bq, bk, bv, relh, relw);
    k_attn<<<1024, 256, 0, stream>>>(qkv, ao);
    k_ln1<<<16384, 256, 0, stream>>>(x, ao, g1, bb1, h1);
    k_gemm<1><<<512 * 16, 256, 0, stream>>>(h1, w1T, u,   512,  2048, 512, 16, 8, b1, nullptr, nullptr, nullptr, nullptr);
    k_gemm<2><<<512 * 4,  256, 0, stream>>>(u,  w2T, ff2, 2048, 512,  512, 4,  2, b2, nullptr, nullptr, nullptr, nullptr);
    k_ln2<<<16384, 256, 0, stream>>>(h1, ff2, g2, bb2, out);
}

// Round 3
// 721.819 us; speedup vs baseline: 1.1017x; 1.0013x over previous
//
#include <hip/hip_runtime.h>
#include <stdint.h>

typedef unsigned short u16;
typedef __attribute__((ext_vector_type(4))) float f32x4;
typedef __attribute__((ext_vector_type(8))) short bf16x8;   // 8 bf16 in 4 VGPRs (MFMA A/B frag)
typedef __attribute__((ext_vector_type(8))) unsigned short u16x8;

__device__ __forceinline__ u16 f2b(float f) {
    union { float f; unsigned u; } x; x.f = f;
    unsigned r = x.u + 0x7fffu + ((x.u >> 16) & 1u);   // RNE
    return (u16)(r >> 16);
}
__device__ __forceinline__ float b2f(u16 b) {
    union { unsigned u; float f; } x; x.u = ((unsigned)b) << 16;
    return x.f;
}

// ---------------- cast x (f32) -> bf16 ----------------
__global__ __launch_bounds__(256) void k_cast(const float* __restrict__ s, u16* __restrict__ d) {
    size_t i = (size_t)blockIdx.x * 256 + threadIdx.x;   // handles 8 elems
    const f32x4* sp = (const f32x4*)(s + i * 8);
    f32x4 a = sp[0], b = sp[1];
    u16x8 o;
    o[0] = f2b(a[0]); o[1] = f2b(a[1]); o[2] = f2b(a[2]); o[3] = f2b(a[3]);
    o[4] = f2b(b[0]); o[5] = f2b(b[1]); o[6] = f2b(b[2]); o[7] = f2b(b[3]);
    *(u16x8*)(d + i * 8) = o;
}

// ---------- transpose-cast: dst[(off+m)*stride + k] = src[k*M + m] ----------
__global__ __launch_bounds__(256) void k_transpose(const float* __restrict__ src, u16* __restrict__ dst,
                                                   int M, int dstOff, int dstStride) {
    __shared__ float t[32][33];
    int bx = blockIdx.x * 32;   // k
    int by = blockIdx.y * 32;   // m
    int tx = threadIdx.x & 31, ty = threadIdx.x >> 5;
#pragma unroll
    for (int r = 0; r < 32; r += 8)
        t[ty + r][tx] = src[(size_t)(bx + ty + r) * M + by + tx];
    __syncthreads();
#pragma unroll
    for (int r = 0; r < 32; r += 8)
        dst[(size_t)(dstOff + by + ty + r) * dstStride + bx + tx] = f2b(t[tx][ty + r]);
}

// ---- block -> (rowTile, colTile): XCD bijective chunk swizzle (m204) + supertile ----
// Supertile = G row-tiles x all nC col-tiles; consecutive logical ids walk rows
// within a supertile first, so the B col-panel is reused G times back-to-back and
// the G A-panels stay resident in the XCD-local L2 across the nC column sweep.
__device__ __forceinline__ void tile_map(int bid, int nR, int nC, int G, int& tr, int& tc) {
    int nwg = nR * nC;
    int q = nwg >> 3, r8 = nwg & 7;
    int xcd = bid & 7, idx = bid >> 3;
    int swz = (xcd < r8 ? xcd * (q + 1) : r8 * (q + 1) + (xcd - r8) * q) + idx;
    int per = G * nC;
    int s = swz / per, w = swz % per;
    int rbase = s * G;
    int g = nR - rbase; if (g > G) g = G;   // tail supertile
    tr = rbase + w % g;
    tc = w / g;
}

// ---------------- GEMM: C[N,M](bf16) = A[N,K](bf16) @ BT[M,K](bf16)^T + epilogue ----------------
// EPI 0: QKV (bias cat + rel_h/rel_w). EPI 1: bias + exact GELU. EPI 2: bias.
template<int EPI>
__global__ __launch_bounds__(256) void k_gemm(
    const u16* __restrict__ A, const u16* __restrict__ BT, u16* __restrict__ C, int K,
    int M, int nR, int nC, int G,
    const float* __restrict__ bias0, const float* __restrict__ bias1, const float* __restrict__ bias2,
    const float* __restrict__ relh, const float* __restrict__ relw)
{
    __shared__ __align__(16) u16 As[128 * 64];
    __shared__ __align__(16) u16 Bs[128 * 64];
    const int lane = threadIdx.x & 63;
    const int wid  = threadIdx.x >> 6;
    int tr, tc;
    tile_map((int)blockIdx.x, nR, nC, G, tr, tc);
    const int rowBase = tr * 128;
    const int colBase = tc * 128;
    const int wr = (wid >> 1) * 64;
    const int wc = (wid & 1) * 64;

    // staging: inst i covers rows i*8..i*8+8 of the tile; lane l -> row i*8+(l>>3),
    // LDS chunk (l&7). XOR-swizzle (T2): LDS slot chunk s of row r holds logical
    // chunk s^(r&7) -> pre-swizzle the GLOBAL source column (gload_lds writes linearly).
    const int srow   = lane >> 3;
    const int schunk = (lane & 7) ^ srow;

    f32x4 acc[4][4] = {};

    const u16* gA = A  + (size_t)(rowBase + srow) * K + schunk * 8;
    const u16* gB = BT + (size_t)(colBase + srow) * K + schunk * 8;

    for (int k0 = 0; k0 < K; k0 += 64) {
#pragma unroll
        for (int i = 0; i < 4; ++i) {
            int ii = i * 4 + wid;
            __builtin_amdgcn_global_load_lds(
                (const __attribute__((address_space(1))) void*)(gA + (size_t)ii * 8 * K + k0),
                (__attribute__((address_space(3))) void*)&As[ii * 512], 16, 0, 0);
            __builtin_amdgcn_global_load_lds(
                (const __attribute__((address_space(1))) void*)(gB + (size_t)ii * 8 * K + k0),
                (__attribute__((address_space(3))) void*)&Bs[ii * 512], 16, 0, 0);
        }
        __syncthreads();
#pragma unroll
        for (int kk = 0; kk < 2; ++kk) {
            const int cc = (kk * 4 + (lane >> 4)) ^ (lane & 7);   // row&7 == lane&7 here
            bf16x8 af[4], bfr[4];
#pragma unroll
            for (int m = 0; m < 4; ++m) {
                int row = wr + m * 16 + (lane & 15);
                af[m] = *(const bf16x8*)&As[row * 64 + cc * 8];
            }
#pragma unroll
            for (int n = 0; n < 4; ++n) {
                int row = wc + n * 16 + (lane & 15);
                bfr[n] = *(const bf16x8*)&Bs[row * 64 + cc * 8];
            }
#pragma unroll
            for (int m = 0; m < 4; ++m)
#pragma unroll
                for (int n = 0; n < 4; ++n)
                    acc[m][n] = __builtin_amdgcn_mfma_f32_16x16x32_bf16(af[m], bfr[n], acc[m][n], 0, 0, 0);
        }
        __syncthreads();
    }

    // epilogue; C/D layout: col = lane&15, row = (lane>>4)*4 + reg  [m89/m91 verified]
#pragma unroll
    for (int m = 0; m < 4; ++m) {
        int grow0 = rowBase + wr + m * 16 + ((lane >> 4) << 2);
#pragma unroll
        for (int n = 0; n < 4; ++n) {
            int gcol = colBase + wc + n * 16 + (lane & 15);
            float badd;
            if (EPI == 0) {
                badd = (gcol < 64) ? bias0[gcol] : (gcol < 128 ? bias1[gcol - 64] : bias2[gcol - 128]);
            } else {
                badd = bias0[gcol];
            }
#pragma unroll
            for (int p = 0; p < 4; ++p) {
                int r = grow0 + p;
                float v = acc[m][n][p] + badd;
                if (EPI == 0) {
                    if (gcol < 64)        v += relh[(((r >> 6) & 63) << 6) + gcol];
                    else if (gcol < 128)  v += relw[((r & 63) << 6) + (gcol - 64)];
                } else if (EPI == 1) {
                    v = 0.5f * v * (1.0f + erff(v * 0.70710678118654752f));
                }
                C[(size_t)r * M + gcol] = f2b(v);
            }
        }
    }
}

// ---------------- axial attention: one block per (b,h); W=64, d=64, E=512 ----------------
__global__ __launch_bounds__(256) void k_attn(const u16* __restrict__ qkv, u16* __restrict__ ao) {
    __shared__ __align__(16) u16 vsT[512 * 64];   // v transposed [col E][row W], XOR-swizzled
    __shared__ __align__(16) u16 ps[64 * 72];     // P bf16, padded stride 72
    const int lane = threadIdx.x & 63;
    const int wid  = threadIdx.x >> 6;
    const int t    = threadIdx.x;
    const size_t base = (size_t)blockIdx.x * 64;

    // stage v (cols 128..640 of qkv rows) transposed into LDS, swizzled chunks
    for (int it = 0; it < 16; ++it) {
        int idx = t + it * 256;
        int j   = idx >> 6;            // v row (width pos)
        int c0  = (idx & 63) * 8;      // v col chunk
        bf16x8 vv = *(const bf16x8*)(qkv + (base + j) * 640 + 128 + c0);
#pragma unroll
        for (int e = 0; e < 8; ++e) {
            int c = c0 + e;
            vsT[c * 64 + (j ^ ((c & 7) << 3))] = (u16)vv[e];
        }
    }

    // S = q k^T for this wave's 16 query rows (frags straight from global, NT pattern)
    const int r0 = wid * 16;
    const int g  = lane >> 4;
    bf16x8 qa[2];
#pragma unroll
    for (int kk = 0; kk < 2; ++kk)
        qa[kk] = *(const bf16x8*)(qkv + (base + r0 + (lane & 15)) * 640 + kk * 32 + (g << 3));
    f32x4 s[4] = {};
#pragma unroll
    for (int n = 0; n < 4; ++n)
#pragma unroll
        for (int kk = 0; kk < 2; ++kk) {
            bf16x8 kb = *(const bf16x8*)(qkv + (base + n * 16 + (lane & 15)) * 640 + 64 + kk * 32 + (g << 3));
            s[n] = __builtin_amdgcn_mfma_f32_16x16x32_bf16(qa[kk], kb, s[n], 0, 0, 0);
        }

    // wave-parallel softmax over 64 cols; row r=(r0+g*4+p) lives in 16 lanes (same g)
    float mx[4], sm[4], inv[4];
    float pe[4][4];
#pragma unroll
    for (int p = 0; p < 4; ++p)
        mx[p] = fmaxf(fmaxf(s[0][p], s[1][p]), fmaxf(s[2][p], s[3][p]));
#pragma unroll
    for (int d = 1; d < 16; d <<= 1)
#pragma unroll
        for (int p = 0; p < 4; ++p) mx[p] = fmaxf(mx[p], __shfl_xor(mx[p], d));
#pragma unroll
    for (int p = 0; p < 4; ++p) sm[p] = 0.f;
#pragma unroll
    for (int n = 0; n < 4; ++n)
#pragma unroll
        for (int p = 0; p < 4; ++p) { pe[n][p] = __expf(s[n][p] - mx[p]); sm[p] += pe[n][p]; }
#pragma unroll
    for (int d = 1; d < 16; d <<= 1)
#pragma unroll
        for (int p = 0; p < 4; ++p) sm[p] += __shfl_xor(sm[p], d);
#pragma unroll
    for (int p = 0; p < 4; ++p) inv[p] = 1.f / sm[p];
#pragma unroll
    for (int n = 0; n < 4; ++n)
#pragma unroll
        for (int p = 0; p < 4; ++p)
            ps[(r0 + (g << 2) + p) * 72 + n * 16 + (lane & 15)] = f2b(pe[n][p] * inv[p]);

    __syncthreads();   // vsT staged by all threads; ps is same-wave

    // O = P @ v : A-frag from own ps rows, B-frag = ds_read_b128 from swizzled vsT
    bf16x8 pa[2];
#pragma unroll
    for (int kk = 0; kk < 2; ++kk)
        pa[kk] = *(const bf16x8*)&ps[(r0 + (lane & 15)) * 72 + kk * 32 + (g << 3)];
    for (int n = 0; n < 32; ++n) {
        f32x4 o = {};
#pragma unroll
        for (int kk = 0; kk < 2; ++kk) {
            int c  = n * 16 + (lane & 15);
            int cl = kk * 4 + g;
            bf16x8 vb = *(const bf16x8*)&vsT[c * 64 + ((cl ^ (c & 7)) << 3)];
            o = __builtin_amdgcn_mfma_f32_16x16x32_bf16(pa[kk], vb, o, 0, 0, 0);
        }
        int col = n * 16 + (lane & 15);
#pragma unroll
        for (int p = 0; p < 4; ++p)
            ao[(base + r0 + (g << 2) + p) * 512 + col] = f2b(o[p]);
    }
}

// ---------------- LN1: h1 = LN(x + ao) -> bf16 ----------------
__global__ __launch_bounds__(256) void k_ln1(const float* __restrict__ x, const u16* __restrict__ ao,
                                             const float* __restrict__ gw, const float* __restrict__ gb,
                                             u16* __restrict__ h1) {
    const int lane = threadIdx.x & 63;
    const size_t row = (size_t)blockIdx.x * 4 + (threadIdx.x >> 6);
    const size_t off = row * 512 + lane * 8;
    f32x4 x0 = *(const f32x4*)(x + off), x1 = *(const f32x4*)(x + off + 4);
    u16x8 a = *(const u16x8*)(ao + off);
    float v[8];
    v[0]=x0[0]+b2f(a[0]); v[1]=x0[1]+b2f(a[1]); v[2]=x0[2]+b2f(a[2]); v[3]=x0[3]+b2f(a[3]);
    v[4]=x1[0]+b2f(a[4]); v[5]=x1[1]+b2f(a[5]); v[6]=x1[2]+b2f(a[6]); v[7]=x1[3]+b2f(a[7]);
    float s = 0.f, q = 0.f;
#pragma unroll
    for (int i = 0; i < 8; ++i) { s += v[i]; q += v[i] * v[i]; }
#pragma unroll
    for (int d = 1; d < 64; d <<= 1) { s += __shfl_xor(s, d); q += __shfl_xor(q, d); }
    float mean = s * (1.f / 512.f);
    float var  = q * (1.f / 512.f) - mean * mean;
    float rstd = rsqrtf(var + 1e-5f);
    u16x8 o;
#pragma unroll
    for (int i = 0; i < 8; ++i)
        o[i] = f2b((v[i] - mean) * rstd * gw[lane * 8 + i] + gb[lane * 8 + i]);
    *(u16x8*)(h1 + off) = o;
}

// ---------------- LN2: out = LN(h1 + ffn) -> f32 ----------------
__global__ __launch_bounds__(256) void k_ln2(const u16* __restrict__ h1, const u16* __restrict__ ff,
                                             const float* __restrict__ gw, const float* __restrict__ gb,
                                             float* __restrict__ out) {
    const int lane = threadIdx.x & 63;
    const size_t row = (size_t)blockIdx.x * 4 + (threadIdx.x >> 6);
    const size_t off = row * 512 + lane * 8;
    u16x8 a = *(const u16x8*)(h1 + off);
    u16x8 c = *(const u16x8*)(ff + off);
    float v[8];
#pragma unroll
    for (int i = 0; i < 8; ++i) v[i] = b2f(a[i]) + b2f(c[i]);
    float s = 0.f, q = 0.f;
#pragma unroll
    for (int i = 0; i < 8; ++i) { s += v[i]; q += v[i] * v[i]; }
#pragma unroll
    for (int d = 1; d < 64; d <<= 1) { s += __shfl_xor(s, d); q += __shfl_xor(q, d); }
    float mean = s * (1.f / 512.f);
    float var  = q * (1.f / 512.f) - mean * mean;
    float rstd = rsqrtf(var + 1e-5f);
    f32x4 o0, o1;
#pragma unroll
    for (int i = 0; i < 4; ++i) o0[i] = (v[i] - mean) * rstd * gw[lane * 8 + i] + gb[lane * 8 + i];
#pragma unroll
    for (int i = 0; i < 4; ++i) o1[i] = (v[4 + i] - mean) * rstd * gw[lane * 8 + 4 + i] + gb[lane * 8 + 4 + i];
    *(f32x4*)(out + off) = o0;
    *(f32x4*)(out + off + 4) = o1;
}

extern "C" void kernel_launch(void* const* d_in, const int* in_sizes, int n_in,
                              void* d_out, int out_size, void* d_ws, size_t ws_size,
                              hipStream_t stream) {
    const float* x    = (const float*)d_in[0];
    const float* Wq   = (const float*)d_in[1];
    const float* bq   = (const float*)d_in[2];
    const float* Wk   = (const float*)d_in[3];
    const float* bk   = (const float*)d_in[4];
    const float* Wv   = (const float*)d_in[5];
    const float* bv   = (const float*)d_in[6];
    const float* relh = (const float*)d_in[7];
    const float* relw = (const float*)d_in[8];
    const float* g1   = (const float*)d_in[9];
    const float* bb1  = (const float*)d_in[10];
    const float* W1   = (const float*)d_in[11];
    const float* b1   = (const float*)d_in[12];
    const float* W2   = (const float*)d_in[13];
    const float* b2   = (const float*)d_in[14];
    const float* g2   = (const float*)d_in[15];
    const float* bb2  = (const float*)d_in[16];
    float* out = (float*)d_out;

    // workspace layout (407,502,848 bytes total); u aliases dead xb/qkv/ao regions
    char* ws = (char*)d_ws;
    u16* u     = (u16*)(ws + 0);                        // [N][2048] bf16, FFN mid
    u16* xb    = (u16*)(ws + 0);                        // [N][512]  (dead before u written)
    u16* qkv   = (u16*)(ws + 67108864ull);              // [N][640]  (dead before u written)
    u16* ao    = (u16*)(ws + 150994944ull);             // [N][512]  (dead before u written)
    u16* h1    = (u16*)(ws + 268435456ull);             // [N][512]
    u16* ff2   = (u16*)(ws + 335544320ull);             // [N][512]
    u16* wqkvT = (u16*)(ws + 402653184ull);             // [640][512]
    u16* w1T   = (u16*)(ws + 403308544ull);             // [2048][512]
    u16* w2T   = (u16*)(ws + 405405696ull);             // [512][2048]

    // weight transposes (bf16, B^T layout for NT GEMM)
    k_transpose<<<dim3(16, 2),  256, 0, stream>>>(Wq, wqkvT, 64,   0,   512);
    k_transpose<<<dim3(16, 2),  256, 0, stream>>>(Wk, wqkvT, 64,   64,  512);
    k_transpose<<<dim3(16, 16), 256, 0, stream>>>(Wv, wqkvT, 512,  128, 512);
    k_transpose<<<dim3(16, 64), 256, 0, stream>>>(W1, w1T,   2048, 0,   512);
    k_transpose<<<dim3(64, 16), 256, 0, stream>>>(W2, w2T,   512,  0,   2048);

    k_cast<<<16384, 256, 0, stream>>>(x, xb);

    // fused QKV projection (+bias, +rel_h on q, +rel_w on k): [N][640]
    // G chosen so supertile working set (G*128*K*2 + nC*128*K*2 bytes) fits one XCD's 4MB L2
    k_gemm<0><<<512 * 5,  256, 0, stream>>>(xb, wqkvT, qkv, 512,  640,  512, 5,  8, bq, bk, bv, relh, relw);
    k_attn<<<1024, 256, 0, stream>>>(qkv, ao);
    k_ln1<<<16384, 256, 0, stream>>>(x, ao, g1, bb1, h1);
    k_gemm<1><<<512 * 16, 256, 0, stream>>>(h1, w1T, u,   512,  2048, 512, 16, 8, b1, nullptr, nullptr, nullptr, nullptr);
    k_gemm<2><<<512 * 4,  256, 0, stream>>>(u,  w2T, ff2, 2048, 512,  512, 4,  2, b2, nullptr, nullptr, nullptr, nullptr);
    k_ln2<<<16384, 256, 0, stream>>>(h1, ff2, g2, bb2, out);
}